// Round 6
// baseline (2419.328 us; speedup 1.0000x reference)
//
#include <hip/hip_runtime.h>
#include <stdint.h>

#define S_ 1024
#define D_ 1024
#define H_ 16
#define DH_ 64
#define FF_ 4096
#define B_ 2
#define V_ 32000
#define CTX_ 1025
#define PAD_ 3

typedef unsigned short u16;
typedef __attribute__((ext_vector_type(8))) short bf16x8;
typedef __attribute__((ext_vector_type(4))) float f32x4;

enum { EPI_BF16 = 0, EPI_QKV = 1, EPI_FC = 2, EPI_GELU_BF16 = 3, EPI_GELU_RES = 4, EPI_BIAS_F32 = 5 };

__device__ __forceinline__ u16 f2bf(float f) {
  unsigned u = __float_as_uint(f);
  return (u16)((u + 0x7FFFu + ((u >> 16) & 1u)) >> 16);
}

__device__ __forceinline__ float bf2f(u16 v) {
  return __uint_as_float(((unsigned)v) << 16);
}

__device__ __forceinline__ float gelu_f(float x) {
  float t = tanhf(0.7978845608028654f * (x + 0.044715f * x * x * x));
  return 0.5f * x * (1.0f + t);
}

__device__ __forceinline__ void glds16(const void* g, void* l) {
  __builtin_amdgcn_global_load_lds(
      (const __attribute__((address_space(1))) unsigned int*)g,
      (__attribute__((address_space(3))) unsigned int*)l,
      16, 0, 0);
}

// ---------------- embedding gather ----------------
__global__ __launch_bounds__(256) void embed_gather(const int* __restrict__ text,
                                                    const float* __restrict__ emb,
                                                    float* __restrict__ x) {
  int row = blockIdx.x;             // 0..2047  (b*1024 + s)
  int b = row >> 10, s = row & 1023;
  int id = text[b * CTX_ + s];
  float4 v = ((const float4*)(emb + (size_t)id * D_))[threadIdx.x];
  ((float4*)(x + (size_t)row * D_))[threadIdx.x] = v;
}

// ---------------- relative positional encoding (bf16) ----------------
__global__ __launch_bounds__(256) void rel_enc(u16* __restrict__ rel) {
  int i = blockIdx.x;               // 0..1023
  float pos = (float)(S_ - 1 - i);
  for (int t = threadIdx.x; t < 512; t += 256) {
    float invf = exp2f(-(float)t * (13.287712379549449f / 512.0f)); // 10000^(-t/512)
    float ang = pos * invf;
    rel[(size_t)i * D_ + t] = f2bf(sinf(ang));
    rel[(size_t)i * D_ + 512 + t] = f2bf(cosf(ang));
  }
}

// ---------------- weight convert f32 (K,N) -> bf16 (N,K), z-batched ----------------
__global__ __launch_bounds__(256) void wconv_t(const float* __restrict__ src,
                                               u16* __restrict__ dst, int K, int N) {
  src += (size_t)blockIdx.z * K * N;
  dst += (size_t)blockIdx.z * K * N;
  __shared__ float tile[32][33];
  int n0 = blockIdx.x * 32, k0 = blockIdx.y * 32;
  for (int idx = threadIdx.x; idx < 1024; idx += 256) {
    int r = idx >> 5, c = idx & 31;                 // r: k, c: n
    tile[r][c] = src[(size_t)(k0 + r) * N + n0 + c];
  }
  __syncthreads();
  for (int idx = threadIdx.x; idx < 1024; idx += 256) {
    int r = idx >> 5, c = idx & 31;                 // r: n, c: k
    dst[(size_t)(n0 + r) * K + k0 + c] = f2bf(tile[c][r]);
  }
}

// ---------------- 4-way weight convert (Wq,Wk,Wv -> qkv segments; Wfc -> fc) ----------------
__global__ __launch_bounds__(256) void wconv4_k(const float* __restrict__ sq,
                                                const float* __restrict__ sk,
                                                const float* __restrict__ sv,
                                                const float* __restrict__ sf,
                                                u16* __restrict__ dqkv,
                                                u16* __restrict__ dfc) {
  const int z = blockIdx.z;
  const float* src = (z == 0) ? sq : (z == 1) ? sk : (z == 2) ? sv : sf;
  u16* dst = (z < 3) ? dqkv + (size_t)z * 1024 * 1024 : dfc;
  __shared__ float tile[32][33];
  int n0 = blockIdx.x * 32, k0 = blockIdx.y * 32;
  for (int idx = threadIdx.x; idx < 1024; idx += 256) {
    int r = idx >> 5, c = idx & 31;
    tile[r][c] = src[(size_t)(k0 + r) * 1024 + n0 + c];
  }
  __syncthreads();
  for (int idx = threadIdx.x; idx < 1024; idx += 256) {
    int r = idx >> 5, c = idx & 31;
    dst[(size_t)(n0 + r) * 1024 + k0 + c] = f2bf(tile[c][r]);
  }
}

// ---------------- layernorm (block per row) ----------------
__global__ __launch_bounds__(256) void layernorm_k(const float* __restrict__ x,
                                                   const float* __restrict__ g,
                                                   const float* __restrict__ bb,
                                                   float* __restrict__ outf,
                                                   u16* __restrict__ outb) {
  int row = blockIdx.x, tid = threadIdx.x;
  const float* xr = x + (size_t)row * D_;
  float4 v = ((const float4*)xr)[tid];
  float s = v.x + v.y + v.z + v.w;
  float s2 = v.x * v.x + v.y * v.y + v.z * v.z + v.w * v.w;
  __shared__ float red[8];
#pragma unroll
  for (int off = 32; off > 0; off >>= 1) { s += __shfl_xor(s, off); s2 += __shfl_xor(s2, off); }
  if ((tid & 63) == 0) { red[tid >> 6] = s; red[4 + (tid >> 6)] = s2; }
  __syncthreads();
  s = red[0] + red[1] + red[2] + red[3];
  s2 = red[4] + red[5] + red[6] + red[7];
  float mean = s * (1.0f / D_);
  float var = s2 * (1.0f / D_) - mean * mean;
  float rstd = rsqrtf(var + 1e-5f);
  float4 gv = ((const float4*)g)[tid];
  float4 bv = ((const float4*)bb)[tid];
  float y0 = (v.x - mean) * rstd * gv.x + bv.x;
  float y1 = (v.y - mean) * rstd * gv.y + bv.y;
  float y2 = (v.z - mean) * rstd * gv.z + bv.z;
  float y3 = (v.w - mean) * rstd * gv.w + bv.w;
  if (outf) ((float4*)(outf + (size_t)row * D_))[tid] = make_float4(y0, y1, y2, y3);
  ((ushort4*)(outb + (size_t)row * D_))[tid] = make_ushort4(f2bf(y0), f2bf(y1), f2bf(y2), f2bf(y3));
}

// ---------------- shared GEMM epilogue ----------------
__device__ __forceinline__ void epi_one(int mode, float v, int row, int col, int ldc,
                                        void* C0p, void* C1p, void* C2p, void* C3p,
                                        const float* bias0, const float* bias1,
                                        const float* res0) {
  if (mode == EPI_QKV) {
    // cols [0,1024): Q -> qu=q+u, qv=q+v ; [1024,2048): K ; [2048,3072): V -> vT transposed
    int seg = col >> 10, c = col & 1023;
    if (seg == 0) {
      size_t idx = (size_t)row * 1024 + c;
      ((u16*)C0p)[idx] = f2bf(v + bias0[c]);
      ((u16*)C1p)[idx] = f2bf(v + bias1[c]);
    } else if (seg == 1) {
      ((u16*)C2p)[(size_t)row * 1024 + c] = f2bf(v);
    } else {
      int d = c & 63, hh = c >> 6;                  // vT[b][h][d][s]
      size_t idx = (((size_t)((row >> 10) * 16 + hh) * 64 + d) << 10) + (row & 1023);
      ((u16*)C3p)[idx] = f2bf(v);
    }
    return;
  }
  size_t idx = (size_t)row * ldc + col;
  float b0 = bias0 ? bias0[col] : 0.0f;
  if (mode == EPI_BF16) {
    ((u16*)C0p)[idx] = f2bf(v);
  } else if (mode == EPI_FC) {
    float* C0 = (float*)C0p;
    C0[idx] = C0[idx] + v + b0 + res0[idx];
  } else if (mode == EPI_GELU_BF16) {
    ((u16*)C0p)[idx] = f2bf(gelu_f(v + b0));
  } else if (mode == EPI_GELU_RES) {
    float* C0 = (float*)C0p;
    C0[idx] = C0[idx] + gelu_f(v + b0);
  } else { // EPI_BIAS_F32
    ((float*)C0p)[idx] = v + b0;
  }
}

// ---------------- GEMM BK=32 variant (LM head: occupancy-rich, 16KB LDS) ----------------
// 128x128 tile, 4 waves (2x2). XCD column-clustering swizzle.
__global__ __launch_bounds__(256) void gemm_bt32(const u16* __restrict__ A,
                                                 const u16* __restrict__ Bt,
                                                 int M, int N, int K,
                                                 void* __restrict__ C0p, void* __restrict__ C1p,
                                                 void* __restrict__ C2p, void* __restrict__ C3p,
                                                 const float* __restrict__ bias0,
                                                 const float* __restrict__ bias1,
                                                 const float* __restrict__ res0,
                                                 int ldc, int mode) {
  __shared__ u16 lA[128 * 32];
  __shared__ u16 lB[128 * 32];
  const int tid = threadIdx.x;
  const int wave = tid >> 6, lane = tid & 63;
  unsigned gx = gridDim.x, gy = gridDim.y;
  unsigned nwg = gx * gy;
  unsigned bx = blockIdx.x, by = blockIdx.y;
  if ((nwg & 7u) == 0u) {
    unsigned lin = by * gx + bx;
    unsigned v = (lin & 7u) * (nwg >> 3) + (lin >> 3);
    bx = v / gy;            // column tile (consecutive v share a column)
    by = v - bx * gy;       // row tile
  }
  const int i0 = by * 128, j0 = bx * 128;
  const int wm = wave & 1, wn = wave >> 1;
  const int m_lane = lane & 15, quad = lane >> 4;

  f32x4 acc[4][4] = {};

  const u16* Ab = A + (size_t)i0 * K;
  const u16* Bb = Bt + (size_t)j0 * K;
  const int r0 = wave * 32 + (lane >> 2);
  const int cb = (lane & 3) * 8;

  for (int k0 = 0; k0 < K; k0 += 32) {
    glds16(Ab + (size_t)r0 * K + k0 + cb, lA + wave * 1024);
    glds16(Ab + (size_t)(r0 + 16) * K + k0 + cb, lA + wave * 1024 + 512);
    glds16(Bb + (size_t)r0 * K + k0 + cb, lB + wave * 1024);
    glds16(Bb + (size_t)(r0 + 16) * K + k0 + cb, lB + wave * 1024 + 512);
    __syncthreads();
    bf16x8 af[4], bfr[4];
#pragma unroll
    for (int t = 0; t < 4; t++) {
      af[t] = *(const bf16x8*)(lA + (wm * 64 + t * 16 + m_lane) * 32 + quad * 8);
      bfr[t] = *(const bf16x8*)(lB + (wn * 64 + t * 16 + m_lane) * 32 + quad * 8);
    }
#pragma unroll
    for (int mt = 0; mt < 4; mt++)
#pragma unroll
      for (int nt = 0; nt < 4; nt++)
        acc[mt][nt] = __builtin_amdgcn_mfma_f32_16x16x32_bf16(af[mt], bfr[nt], acc[mt][nt], 0, 0, 0);
    __syncthreads();
  }

#pragma unroll
  for (int mt = 0; mt < 4; mt++) {
#pragma unroll
    for (int nt = 0; nt < 4; nt++) {
      int col = j0 + wn * 64 + nt * 16 + m_lane;
#pragma unroll
      for (int r = 0; r < 4; r++) {
        int row = i0 + wm * 64 + mt * 16 + quad * 4 + r;
        epi_one(mode, acc[mt][nt][r], row, col, ldc, C0p, C1p, C2p, C3p, bias0, bias1, res0);
      }
    }
  }
}

// ---------------- main GEMM BK=64 (latency-bound mid GEMMs: half the barriers) ----------------
// 128x128 tile; swizzled LDS (pre-swizzled global source + swizzled ds_read).
__global__ __launch_bounds__(256) void gemm_bt(const u16* __restrict__ A,
                                               const u16* __restrict__ Bt,
                                               int M, int N, int K,
                                               void* __restrict__ C0p, void* __restrict__ C1p,
                                               void* __restrict__ C2p, void* __restrict__ C3p,
                                               const float* __restrict__ bias0,
                                               const float* __restrict__ bias1,
                                               const float* __restrict__ res0,
                                               int ldc, int mode) {
  __shared__ u16 lA[128 * 64];
  __shared__ u16 lB[128 * 64];
  const int tid = threadIdx.x;
  const int wave = tid >> 6, lane = tid & 63;
  unsigned gx = gridDim.x, gy = gridDim.y;
  unsigned nwg = gx * gy;
  unsigned bx = blockIdx.x, by = blockIdx.y;
  if ((nwg & 7u) == 0u) {
    unsigned lin = by * gx + bx;
    unsigned v = (lin & 7u) * (nwg >> 3) + (lin >> 3);
    bx = v / gy;            // column tile (consecutive v share a column)
    by = v - bx * gy;       // row tile
  }
  const int i0 = by * 128, j0 = bx * 128;
  const int wm = wave & 1, wn = wave >> 1;
  const int m_lane = lane & 15, quad = lane >> 4;

  f32x4 acc[4][4] = {};

  const u16* Ab = A + (size_t)i0 * K;
  const u16* Bb = Bt + (size_t)j0 * K;
  const int sr = lane >> 3;                       // 0..7 row within 8-row stage group
  const int sc = ((lane & 7) ^ sr) * 8;           // pre-swizzled source u16 col

  for (int k0 = 0; k0 < K; k0 += 64) {
#pragma unroll
    for (int c = 0; c < 4; c++) {
      int row = wave * 32 + c * 8 + sr;           // row&7 == sr
      glds16(Ab + (size_t)row * K + k0 + sc, lA + (size_t)(wave * 32 + c * 8) * 64);
      glds16(Bb + (size_t)row * K + k0 + sc, lB + (size_t)(wave * 32 + c * 8) * 64);
    }
    __syncthreads();
    bf16x8 af[4], bfr[4];
#pragma unroll
    for (int t = 0; t < 4; t++) {
      int ra = wm * 64 + t * 16 + m_lane;
      int rb_ = wn * 64 + t * 16 + m_lane;
      af[t]  = *(const bf16x8*)(lA + ra * 64 + ((quad ^ (ra & 7)) * 8));
      bfr[t] = *(const bf16x8*)(lB + rb_ * 64 + ((quad ^ (rb_ & 7)) * 8));
    }
#pragma unroll
    for (int mt = 0; mt < 4; mt++)
#pragma unroll
      for (int nt = 0; nt < 4; nt++)
        acc[mt][nt] = __builtin_amdgcn_mfma_f32_16x16x32_bf16(af[mt], bfr[nt], acc[mt][nt], 0, 0, 0);
#pragma unroll
    for (int t = 0; t < 4; t++) {
      int ra = wm * 64 + t * 16 + m_lane;
      int rb_ = wn * 64 + t * 16 + m_lane;
      af[t]  = *(const bf16x8*)(lA + ra * 64 + (((4 + quad) ^ (ra & 7)) * 8));
      bfr[t] = *(const bf16x8*)(lB + rb_ * 64 + (((4 + quad) ^ (rb_ & 7)) * 8));
    }
#pragma unroll
    for (int mt = 0; mt < 4; mt++)
#pragma unroll
      for (int nt = 0; nt < 4; nt++)
        acc[mt][nt] = __builtin_amdgcn_mfma_f32_16x16x32_bf16(af[mt], bfr[nt], acc[mt][nt], 0, 0, 0);
    __syncthreads();
  }

#pragma unroll
  for (int mt = 0; mt < 4; mt++) {
#pragma unroll
    for (int nt = 0; nt < 4; nt++) {
      int col = j0 + wn * 64 + nt * 16 + m_lane;
#pragma unroll
      for (int r = 0; r < 4; r++) {
        int row = i0 + wm * 64 + mt * 16 + quad * 4 + r;
        epi_one(mode, acc[mt][nt][r], row, col, ldc, C0p, C1p, C2p, C3p, bias0, bias1, res0);
      }
    }
  }
}

// ---------------- 64x128-tile GEMM variant (N=1024 outputs), BK=64 ----------------
// ROW clustering swizzle (A is the big operand for ff2).
__global__ __launch_bounds__(256) void gemm_bt64(const u16* __restrict__ A,
                                                 const u16* __restrict__ Bt,
                                                 int M, int N, int K,
                                                 void* __restrict__ C0p, void* __restrict__ C1p,
                                                 void* __restrict__ C2p, void* __restrict__ C3p,
                                                 const float* __restrict__ bias0,
                                                 const float* __restrict__ bias1,
                                                 const float* __restrict__ res0,
                                                 int ldc, int mode) {
  __shared__ u16 lA[64 * 64];
  __shared__ u16 lB[128 * 64];
  const int tid = threadIdx.x;
  const int wave = tid >> 6, lane = tid & 63;
  unsigned gx = gridDim.x, gy = gridDim.y;
  unsigned nwg = gx * gy;
  unsigned bx = blockIdx.x, by = blockIdx.y;
  if ((nwg & 7u) == 0u) {
    unsigned lin = by * gx + bx;
    unsigned v = (lin & 7u) * (nwg >> 3) + (lin >> 3);
    by = v / gx;            // row tile (consecutive v share a row)
    bx = v - by * gx;       // column tile
  }
  const int i0 = by * 64, j0 = bx * 128;
  const int m_lane = lane & 15, quad = lane >> 4;

  f32x4 acc[4][2] = {};

  const u16* Ab = A + (size_t)i0 * K;
  const u16* Bb = Bt + (size_t)j0 * K;
  const int sr = lane >> 3;
  const int sc = ((lane & 7) ^ sr) * 8;

  for (int k0 = 0; k0 < K; k0 += 64) {
#pragma unroll
    for (int c = 0; c < 2; c++) {
      int row = wave * 16 + c * 8 + sr;           // A rows: 64 total
      glds16(Ab + (size_t)row * K + k0 + sc, lA + (size_t)(wave * 16 + c * 8) * 64);
    }
#pragma unroll
    for (int c = 0; c < 4; c++) {
      int row = wave * 32 + c * 8 + sr;           // B rows: 128 total
      glds16(Bb + (size_t)row * K + k0 + sc, lB + (size_t)(wave * 32 + c * 8) * 64);
    }
    __syncthreads();
    bf16x8 af[4], bfr[2];
#pragma unroll
    for (int t = 0; t < 4; t++) {
      int ra = t * 16 + m_lane;
      af[t] = *(const bf16x8*)(lA + ra * 64 + ((quad ^ (ra & 7)) * 8));
    }
#pragma unroll
    for (int t = 0; t < 2; t++) {
      int rb_ = wave * 32 + t * 16 + m_lane;
      bfr[t] = *(const bf16x8*)(lB + rb_ * 64 + ((quad ^ (rb_ & 7)) * 8));
    }
#pragma unroll
    for (int mt = 0; mt < 4; mt++)
#pragma unroll
      for (int nt = 0; nt < 2; nt++)
        acc[mt][nt] = __builtin_amdgcn_mfma_f32_16x16x32_bf16(af[mt], bfr[nt], acc[mt][nt], 0, 0, 0);
#pragma unroll
    for (int t = 0; t < 4; t++) {
      int ra = t * 16 + m_lane;
      af[t] = *(const bf16x8*)(lA + ra * 64 + (((4 + quad) ^ (ra & 7)) * 8));
    }
#pragma unroll
    for (int t = 0; t < 2; t++) {
      int rb_ = wave * 32 + t * 16 + m_lane;
      bfr[t] = *(const bf16x8*)(lB + rb_ * 64 + (((4 + quad) ^ (rb_ & 7)) * 8));
    }
#pragma unroll
    for (int mt = 0; mt < 4; mt++)
#pragma unroll
      for (int nt = 0; nt < 2; nt++)
        acc[mt][nt] = __builtin_amdgcn_mfma_f32_16x16x32_bf16(af[mt], bfr[nt], acc[mt][nt], 0, 0, 0);
    __syncthreads();
  }

#pragma unroll
  for (int mt = 0; mt < 4; mt++) {
#pragma unroll
    for (int nt = 0; nt < 2; nt++) {
      int col = j0 + wave * 32 + nt * 16 + m_lane;
#pragma unroll
      for (int r = 0; r < 4; r++) {
        int row = i0 + mt * 16 + quad * 4 + r;
        epi_one(mode, acc[mt][nt][r], row, col, ldc, C0p, C1p, C2p, C3p, bias0, bias1, res0);
      }
    }
  }
}

// ---------------- flash attention: AC + rel-shifted BD + online softmax + PV ----------------
// grid (16, 32): bx pairs long/short q-tiles (ti = odd ? bx>>1 : 15-(bx>>1)) so each
// adjacent block pair sums to 15 tiles of work. 4 waves, each owning 16 q-rows.
// No barriers: sBD/sP are written and read intra-wave only. Scores never touch HBM.
__global__ __launch_bounds__(256) void attn_flash(const u16* __restrict__ qu,
                                                  const u16* __restrict__ qv,
                                                  const u16* __restrict__ kk,
                                                  const u16* __restrict__ rb, // + l*1024, row stride 4096
                                                  const u16* __restrict__ vT,
                                                  const int* __restrict__ text,
                                                  u16* __restrict__ o_) {
  __shared__ u16 sBD[64][132];   // rel-shift gather tile
  __shared__ u16 sP[64][72];     // P transpose tile (144B row stride, 16B-aligned)
  const int bx = blockIdx.x, bh = blockIdx.y;
  const int ti = (bx & 1) ? (bx >> 1) : (15 - (bx >> 1));
  const int b = bh >> 4, h = bh & 15;
  const int tid = threadIdx.x, wave = tid >> 6, lane = tid & 63;
  const int m_lane = lane & 15, quad = lane >> 4;
  const int i0 = ti * 64;

  // Q fragments, hoisted (A-operand rows use m_lane)
  const u16* Qu = qu + ((size_t)(b * S_ + i0 + wave * 16 + m_lane)) * D_ + h * DH_ + quad * 8;
  const u16* Qv = qv + ((size_t)(b * S_ + i0 + wave * 16 + m_lane)) * D_ + h * DH_ + quad * 8;
  bf16x8 a0 = *(const bf16x8*)(Qu);
  bf16x8 a1 = *(const bf16x8*)(Qu + 32);
  bf16x8 c0 = *(const bf16x8*)(Qv);
  bf16x8 c1 = *(const bf16x8*)(Qv + 32);

  const u16* vTb = vT + (size_t)bh * DH_ * S_;

  f32x4 oacc[4] = {};                              // [nt(d-block)][r]; rows = quad*4+r
  float m_[4] = {-3e38f, -3e38f, -3e38f, -3e38f};  // running max per row
  float l_[4] = {0.f, 0.f, 0.f, 0.f};              // running sum per row

  for (int tj = 0; tj <= ti; tj++) {
    const int j0 = tj * 64;
    const int T0 = 15 - (ti - tj);
    const bool hasT1 = (T0 < 15);
    const u16* Kb = kk + ((size_t)(b * S_ + j0)) * D_ + h * DH_;
    const u16* R0 = rb + ((size_t)(T0 * 64)) * 4096 + h * DH_;
    const u16* R1 = R0 + (size_t)64 * 4096;

    f32x4 ac_[4] = {}, bd0_[4] = {}, bd1_[4] = {};
    __builtin_amdgcn_s_setprio(1);
#pragma unroll
    for (int nt = 0; nt < 4; nt++) {
      const u16* kr = Kb + (size_t)(nt * 16 + m_lane) * D_ + quad * 8;
      bf16x8 kb0 = *(const bf16x8*)(kr);
      bf16x8 kb1 = *(const bf16x8*)(kr + 32);
      ac_[nt] = __builtin_amdgcn_mfma_f32_16x16x32_bf16(a0, kb0, ac_[nt], 0, 0, 0);
      ac_[nt] = __builtin_amdgcn_mfma_f32_16x16x32_bf16(a1, kb1, ac_[nt], 0, 0, 0);
      const u16* rr = R0 + (size_t)(nt * 16 + m_lane) * 4096 + quad * 8;
      bf16x8 rb0 = *(const bf16x8*)(rr);
      bf16x8 rb1 = *(const bf16x8*)(rr + 32);
      bd0_[nt] = __builtin_amdgcn_mfma_f32_16x16x32_bf16(c0, rb0, bd0_[nt], 0, 0, 0);
      bd0_[nt] = __builtin_amdgcn_mfma_f32_16x16x32_bf16(c1, rb1, bd0_[nt], 0, 0, 0);
      if (hasT1) {
        const u16* r2 = R1 + (size_t)(nt * 16 + m_lane) * 4096 + quad * 8;
        bf16x8 rc0 = *(const bf16x8*)(r2);
        bf16x8 rc1 = *(const bf16x8*)(r2 + 32);
        bd1_[nt] = __builtin_amdgcn_mfma_f32_16x16x32_bf16(c0, rc0, bd1_[nt], 0, 0, 0);
        bd1_[nt] = __builtin_amdgcn_mfma_f32_16x16x32_bf16(c1, rc1, bd1_[nt], 0, 0, 0);
      }
    }
    __builtin_amdgcn_s_setprio(0);

    // BD (i,t) -> LDS; each wave writes/reads only its own 16 rows (no barrier)
#pragma unroll
    for (int nt = 0; nt < 4; nt++) {
      int col = nt * 16 + m_lane;
#pragma unroll
      for (int r = 0; r < 4; r++) {
        int row = wave * 16 + quad * 4 + r;
        sBD[row][col] = f2bf(bd0_[nt][r]);
        sBD[row][64 + col] = hasT1 ? f2bf(bd1_[nt][r]) : (u16)0;
      }
    }

    // s = (AC + BD)*scale, causal-masked on diagonal tile
    float p_[4][4];   // [nt][r]
#pragma unroll
    for (int nt = 0; nt < 4; nt++) {
      int jl = nt * 16 + m_lane;
#pragma unroll
      for (int r = 0; r < 4; r++) {
        int il = wave * 16 + quad * 4 + r;
        float s = (ac_[nt][r] + bf2f(sBD[il][jl - il + 63])) * 0.125f;
        if (ti == tj && jl > il) s = -3e38f;
        p_[nt][r] = s;
      }
    }

    // online softmax update per row (row state replicated across the 16-lane group)
#pragma unroll
    for (int r = 0; r < 4; r++) {
      float t = fmaxf(fmaxf(p_[0][r], p_[1][r]), fmaxf(p_[2][r], p_[3][r]));
      t = fmaxf(t, __shfl_xor(t, 1));
      t = fmaxf(t, __shfl_xor(t, 2));
      t = fmaxf(t, __shfl_xor(t, 4));
      t = fmaxf(t, __shfl_xor(t, 8));
      float mn = fmaxf(m_[r], t);
      float corr = __expf(m_[r] - mn);
      m_[r] = mn;
      float ts = 0.f;
#pragma unroll
      for (int nt = 0; nt < 4; nt++) {
        float p = __expf(p_[nt][r] - mn);
        p_[nt][r] = p;
        ts += p;
      }
      ts += __shfl_xor(ts, 1);
      ts += __shfl_xor(ts, 2);
      ts += __shfl_xor(ts, 4);
      ts += __shfl_xor(ts, 8);
      l_[r] = l_[r] * corr + ts;
#pragma unroll
      for (int nt = 0; nt < 4; nt++) oacc[nt][r] *= corr;
    }

    // P -> bf16 -> LDS transpose (intra-wave), then PV
#pragma unroll
    for (int nt = 0; nt < 4; nt++) {
      int col = nt * 16 + m_lane;
#pragma unroll
      for (int r = 0; r < 4; r++)
        sP[wave * 16 + quad * 4 + r][col] = f2bf(p_[nt][r]);
    }
    bf16x8 pa0 = *(const bf16x8*)(&sP[wave * 16 + m_lane][quad * 8]);
    bf16x8 pa1 = *(const bf16x8*)(&sP[wave * 16 + m_lane][32 + quad * 8]);
    __builtin_amdgcn_s_setprio(1);
#pragma unroll
    for (int nt = 0; nt < 4; nt++) {
      const u16* vr = vTb + (size_t)(nt * 16 + m_lane) * S_ + j0 + quad * 8;
      bf16x8 bv0 = *(const bf16x8*)(vr);
      bf16x8 bv1 = *(const bf16x8*)(vr + 32);
      oacc[nt] = __builtin_amdgcn_mfma_f32_16x16x32_bf16(pa0, bv0, oacc[nt], 0, 0, 0);
      oacc[nt] = __builtin_amdgcn_mfma_f32_16x16x32_bf16(pa1, bv1, oacc[nt], 0, 0, 0);
    }
    __builtin_amdgcn_s_setprio(0);
  }

  // normalize and write (PAD query rows -> 0)
  u16* Ob = o_ + (size_t)b * S_ * D_ + h * DH_;
#pragma unroll
  for (int r = 0; r < 4; r++) {
    int row = i0 + wave * 16 + quad * 4 + r;
    bool pad = (text[b * CTX_ + row] == PAD_);
    float inv = pad ? 0.0f : (1.0f / l_[r]);
#pragma unroll
    for (int nt = 0; nt < 4; nt++)
      Ob[(size_t)row * D_ + nt * 16 + m_lane] = f2bf(oacc[nt][r] * inv);
  }
}

// =====================================================================
extern "C" void kernel_launch(void* const* d_in, const int* in_sizes, int n_in,
                              void* d_out, int out_size, void* d_ws, size_t ws_size,
                              hipStream_t stream) {
  (void)in_sizes; (void)n_in; (void)out_size;
  const int* text = (const int*)d_in[0];
  const float* emb = (const float*)d_in[1];
  const float* u_in = (const float*)d_in[2];
  const float* v_in = (const float*)d_in[3];
  const float* Wq = (const float*)d_in[4];
  const float* Wk = (const float*)d_in[5];
  const float* Wv = (const float*)d_in[6];
  const float* Wr = (const float*)d_in[7];
  const float* Wfc = (const float*)d_in[8];
  const float* bfc = (const float*)d_in[9];
  const float* ln1g = (const float*)d_in[10];
  const float* ln1b = (const float*)d_in[11];
  const float* ln2g = (const float*)d_in[12];
  const float* ln2b = (const float*)d_in[13];
  const float* W1 = (const float*)d_in[14];
  const float* b1 = (const float*)d_in[15];
  const float* W2 = (const float*)d_in[16];
  const float* b2 = (const float*)d_in[17];
  const float* lnfg = (const float*)d_in[18];
  const float* lnfb = (const float*)d_in[19];
  const float* Wlm = (const float*)d_in[20];
  const float* blm = (const float*)d_in[21];
  float* out = (float*)d_out;

  char* w = (char*)d_ws;
  size_t off = 0;
  auto alloc = [&](size_t bytes) -> void* {
    void* p = w + off;
    off += (bytes + 255) & ~(size_t)255;
    return p;
  };
  float* x      = (float*)alloc(2048ull * 1024 * 4);
  float* xnf    = (float*)alloc(2048ull * 1024 * 4);
  u16* xnb      = (u16*)alloc(2048ull * 1024 * 2);
  u16* relb     = (u16*)alloc(1024ull * 1024 * 2);
  u16* wqkvt    = (u16*)alloc(3072ull * 1024 * 2);   // [Wq^T | Wk^T | Wv^T]
  u16* wrt_all  = (u16*)alloc(4096ull * 1024 * 2);   // all 4 layers' Wr^T
  u16* wfct     = (u16*)alloc(1024ull * 1024 * 2);
  u16* w1t      = (u16*)alloc(4096ull * 1024 * 2);
  u16* w2t      = (u16*)alloc(4096ull * 1024 * 2);
  u16* wlmt     = (u16*)alloc(32000ull * 1024 * 2);
  u16* qu       = (u16*)alloc(2048ull * 1024 * 2);
  u16* qv       = (u16*)alloc(2048ull * 1024 * 2);
  u16* kk       = (u16*)alloc(2048ull * 1024 * 2);
  u16* vT       = (u16*)alloc(2048ull * 1024 * 2);
  u16* rb_all   = (u16*)alloc(1024ull * 4096 * 2);   // rel @ Wr[l], all layers (ldc=4096)
  u16* o_       = (u16*)alloc(2048ull * 1024 * 2);
  u16* f1       = (u16*)alloc(2048ull * 4096 * 2);
  if (off > ws_size) return;  // workspace too small; fail loudly via wrong output

  dim3 blk(256);
  embed_gather<<<2048, blk, 0, stream>>>(text, emb, x);
  rel_enc<<<1024, blk, 0, stream>>>(relb);
  wconv_t<<<dim3(1000, 32), blk, 0, stream>>>(Wlm, wlmt, 1024, 32000);
  // all 4 layers' Wr^T, then one batched R projection: rb_all = rel @ [Wr0|Wr1|Wr2|Wr3]
  wconv_t<<<dim3(32, 32, 4), blk, 0, stream>>>(Wr, wrt_all, 1024, 1024);
  gemm_bt<<<dim3(32, 8), blk, 0, stream>>>(relb, wrt_all, 1024, 4096, 1024,
                                           rb_all, nullptr, nullptr, nullptr,
                                           nullptr, nullptr, nullptr, 4096, EPI_BF16);

  for (int l = 0; l < 4; l++) {
    const size_t dd = 1048576;  // D*D
    wconv4_k<<<dim3(32, 32, 4), blk, 0, stream>>>(Wq + l * dd, Wk + l * dd, Wv + l * dd,
                                                  Wfc + l * dd, wqkvt, wfct);
    wconv_t<<<dim3(128, 32), blk, 0, stream>>>(W1 + l * 4ull * dd, w1t, 1024, 4096);
    wconv_t<<<dim3(32, 128), blk, 0, stream>>>(W2 + l * 4ull * dd, w2t, 4096, 1024);

    layernorm_k<<<2048, blk, 0, stream>>>(x, ln1g + l * 1024, ln1b + l * 1024, xnf, xnb);

    // fused Q/K/V projection: N=3072; V written transposed into vT
    gemm_bt<<<dim3(24, 16), blk, 0, stream>>>(xnb, wqkvt, 2048, 3072, 1024,
                                              qu, qv, kk, vT, u_in, v_in, nullptr, 1024, EPI_QKV);

    // flash attention: scores never hit HBM
    attn_flash<<<dim3(16, 32), blk, 0, stream>>>(qu, qv, kk, rb_all + (size_t)l * 1024,
                                                 vT, text, o_);

    gemm_bt64<<<dim3(8, 32), blk, 0, stream>>>(o_, wfct, 2048, 1024, 1024,
                                               x, nullptr, nullptr, nullptr,
                                               bfc + l * 1024, nullptr, xnf, 1024, EPI_FC);
    layernorm_k<<<2048, blk, 0, stream>>>(x, ln2g + l * 1024, ln2b + l * 1024, nullptr, xnb);
    gemm_bt<<<dim3(32, 16), blk, 0, stream>>>(xnb, w1t, 2048, 4096, 1024,
                                              f1, nullptr, nullptr, nullptr,
                                              b1 + l * 4096, nullptr, nullptr, 4096, EPI_GELU_BF16);
    gemm_bt64<<<dim3(8, 32), blk, 0, stream>>>(f1, w2t, 2048, 1024, 4096,
                                               x, nullptr, nullptr, nullptr,
                                               b2 + l * 1024, nullptr, nullptr, 1024, EPI_GELU_RES);
  }

  layernorm_k<<<2048, blk, 0, stream>>>(x, lnfg, lnfb, nullptr, xnb);
  gemm_bt32<<<dim3(250, 16), blk, 0, stream>>>(xnb, wlmt, 2048, 32000, 1024,
                                               out, nullptr, nullptr, nullptr,
                                               blm, nullptr, nullptr, 32000, EPI_BIAS_F32);
}